// Round 1
// baseline (2230.490 us; speedup 1.0000x reference)
//
#include <hip/hip_runtime.h>
#include <math.h>
#include <float.h>

// ---- problem constants (N=1, C=1, 256x256, sigma scalar) ----
constexpr int IMG  = 256;            // H = W
constexpr int PADR = 21;             // p//2 + w//2 = 3 + 18
constexpr int PDIM = IMG + 2*PADR;   // 298
constexpr int XDIM = PDIM - 7 + 1;   // 292  (unfold spatial dim)
constexpr int LTOT = XDIM * XDIM;    // 85264
constexpr int WSZ  = 37;             // search window
constexpr int INC  = 18;             // WSZ/2
constexpr int ST   = 4;              // stride
constexpr int GDIM = 64;             // query grid per dim (256/4)
constexpr int NBLK = GDIM * GDIM;    // 4096
constexpr int PS   = 7;              // patch size
constexpr int PP   = 49;             // patch pixels
constexpr int MM1  = 18;
constexpr int MM2  = 55;
constexpr int RG   = 43;             // search region = 2*INC + PS

// ---------------- reflect pad: src (IMG x IMG) -> dst (PDIM x PDIM) ----------
__global__ void pad_reflect(const float* __restrict__ src, float* __restrict__ dst)
{
    int idx = blockIdx.x * 256 + threadIdx.x;
    if (idx >= PDIM * PDIM) return;
    int y = idx / PDIM, x = idx % PDIM;
    int oy = y - PADR; oy = (oy < 0) ? -oy : ((oy >= IMG) ? 2*(IMG-1) - oy : oy);
    int ox = x - PADR; ox = (ox < 0) ? -ox : ((ox >= IMG) ? 2*(IMG-1) - ox : ox);
    dst[idx] = src[oy * IMG + ox];
}

// ---------------- block matching: one workgroup per query block -------------
// Query block (gi,gj): patch top-left in padded coords (INC+4gi, INC+4gj).
// Candidate offset (oi,oj) in [0,37)^2 -> patch top-left (oi+4gi, oj+4gj).
// Select m smallest SSD (self offset forced to -1), tie-break lower offset idx.
// Output pos[blk*m + k] = a*XDIM + b  (flat position in 292x292 unfold grid).
__global__ __launch_bounds__(256) void block_match(const float* __restrict__ pad,
                                                   int* __restrict__ pos, int m)
{
    __shared__ float reg[RG][RG + 1];
    __shared__ float dist[WSZ * WSZ];
    __shared__ float sv[4];
    __shared__ int   si[4];

    const int gi = blockIdx.y, gj = blockIdx.x;
    const int tid = threadIdx.x;
    const int r0 = ST * gi, c0 = ST * gj;       // region top-left in padded coords

    for (int t = tid; t < RG * RG; t += 256) {
        int r = t / RG, c = t % RG;
        reg[r][c] = pad[(r0 + r) * PDIM + (c0 + c)];
    }
    __syncthreads();

    // query patch (local coords INC..INC+6) into registers
    float q[PP];
#pragma unroll
    for (int i = 0; i < PS; i++)
#pragma unroll
        for (int j = 0; j < PS; j++)
            q[i * PS + j] = reg[INC + i][INC + j];

    for (int o = tid; o < WSZ * WSZ; o += 256) {
        int oi = o / WSZ, oj = o % WSZ;
        float s = 0.f;
#pragma unroll
        for (int i = 0; i < PS; i++)
#pragma unroll
            for (int j = 0; j < PS; j++) {
                float d = reg[oi + i][oj + j] - q[i * PS + j];
                s += d * d;
            }
        dist[o] = s;
    }
    __syncthreads();
    if (tid == 0) dist[INC * WSZ + INC] = -1.0f;   // self match
    __syncthreads();

    const int blk = gi * GDIM + gj;
    for (int sel = 0; sel < m; sel++) {
        float bv = FLT_MAX; int bi = WSZ * WSZ;
        for (int o = tid; o < WSZ * WSZ; o += 256) {
            float v = dist[o];
            if (v < bv || (v == bv && o < bi)) { bv = v; bi = o; }
        }
        // wave (64-lane) shuffle reduce
        for (int d = 32; d > 0; d >>= 1) {
            float ov = __shfl_down(bv, d);
            int   oo = __shfl_down(bi, d);
            if (ov < bv || (ov == bv && oo < bi)) { bv = ov; bi = oo; }
        }
        if ((tid & 63) == 0) { sv[tid >> 6] = bv; si[tid >> 6] = bi; }
        __syncthreads();
        if (tid == 0) {
            float fv = sv[0]; int fi = si[0];
            for (int wv = 1; wv < 4; wv++)
                if (sv[wv] < fv || (sv[wv] == fv && si[wv] < fi)) { fv = sv[wv]; fi = si[wv]; }
            int oi = fi / WSZ, oj = fi % WSZ;
            pos[blk * m + sel] = (oi + ST * gi) * XDIM + (oj + ST * gj);
            dist[fi] = FLT_MAX;   // remove from further rounds
        }
        __syncthreads();
    }
}

// ---------------- denoise + scatter: one workgroup per group ----------------
// M = Gram(S) (+ c*I if add_c); theta = I - c*M^{-1};
// Xh = Y - c*(M^{-1} Y); w_k = 1/sum_j theta_kj^2.
// Scatter: Xsum[q][pos_k] += w_k * Xh[k][q];  Wacc[pos_k] += w_k.
__global__ __launch_bounds__(256) void denoise_scatter(
    const float* __restrict__ padY, const float* __restrict__ padS,
    const int* __restrict__ pos, const float* __restrict__ sigma_p,
    float* __restrict__ Xsum, float* __restrict__ Wacc,
    int m, int add_c)
{
    extern __shared__ float sm[];
    const int NC  = m + PP;       // columns of [I | Y]
    const int NCp = NC + 1;
    float* Ysh = sm;              // m x 50
    float* Ssh = Ysh + m * 50;    // m x 50
    float* Msh = Ssh + m * 50;    // m x m (lower triangle used)
    float* Zsh = Msh + m * m;     // m x NCp
    float* wsh = Zsh + m * NCp;   // m

    const int tid = threadIdx.x;
    const int blk = blockIdx.x;
    const float sg = *sigma_p;
    const float c  = (float)PP * sg * sg;

    // gather group patches
    for (int t = tid; t < m * PP; t += 256) {
        int k = t / PP, qq = t % PP;
        int p_ = pos[blk * m + k];
        int a = p_ / XDIM, b = p_ % XDIM;
        int g = (a + qq / PS) * PDIM + (b + qq % PS);
        Ysh[k * 50 + qq] = padY[g];
        Ssh[k * 50 + qq] = padS[g];
    }
    __syncthreads();

    // Gram (lower triangle), + ridge on diagonal for stage 2
    for (int t = tid; t < m * m; t += 256) {
        int i = t / m, j = t % m;
        if (j > i) continue;
        float s = 0.f;
        for (int qq = 0; qq < PP; qq++) s += Ssh[i * 50 + qq] * Ssh[j * 50 + qq];
        if (i == j && add_c) s += c;
        Msh[i * m + j] = s;
    }
    __syncthreads();

    // in-place Cholesky (lower)
    for (int k = 0; k < m; k++) {
        if (tid == 0) Msh[k * m + k] = sqrtf(fmaxf(Msh[k * m + k], 1e-20f));
        __syncthreads();
        float pk = Msh[k * m + k];
        for (int r = k + 1 + tid; r < m; r += 256) Msh[r * m + k] /= pk;
        __syncthreads();
        int rem = m - k - 1;
        for (int t = tid; t < rem * rem; t += 256) {
            int r  = k + 1 + t / rem;
            int cc = k + 1 + t % rem;
            if (cc <= r) Msh[r * m + cc] -= Msh[r * m + k] * Msh[cc * m + k];
        }
        __syncthreads();
    }

    // solve M * Z = [I | Ycols]; one thread per column
    if (tid < NC) {
        const int col = tid;
        for (int j = 0; j < m; j++) {               // forward: L z = b
            float b = (col < m) ? (j == col ? 1.f : 0.f) : Ysh[j * 50 + (col - m)];
            float s = b;
            for (int l = 0; l < j; l++) s -= Msh[j * m + l] * Zsh[l * NCp + col];
            Zsh[j * NCp + col] = s / Msh[j * m + j];
        }
        for (int j = m - 1; j >= 0; j--) {          // backward: L^T w = z
            float s = Zsh[j * NCp + col];
            for (int l = j + 1; l < m; l++) s -= Msh[l * m + j] * Zsh[l * NCp + col];
            Zsh[j * NCp + col] = s / Msh[j * m + j];
        }
    }
    __syncthreads();

    // weights: 1 / rowsum(theta^2), theta = I - c*Minv
    for (int k = tid; k < m; k += 256) {
        float s = 0.f;
        for (int j = 0; j < m; j++) {
            float th = ((j == k) ? 1.f : 0.f) - c * Zsh[k * NCp + j];
            s += th * th;
        }
        wsh[k] = 1.f / s;
    }
    __syncthreads();

    // scatter-add weighted denoised patches
    for (int t = tid; t < m * PP; t += 256) {
        int k = t / PP, qq = t % PP;
        int p_ = pos[blk * m + k];
        float xh = Ysh[k * 50 + qq] - c * Zsh[k * NCp + m + qq];
        atomicAdd(&Xsum[qq * LTOT + p_], xh * wsh[k]);
    }
    for (int t = tid; t < m; t += 256)
        atomicAdd(&Wacc[pos[blk * m + t]], wsh[t]);
}

// ---------------- fold (49-tap stencil) + normalize + crop ------------------
__global__ void fold_norm(const float* __restrict__ Xsum, const float* __restrict__ Wacc,
                          float* __restrict__ out)
{
    int idx = blockIdx.x * 256 + threadIdx.x;
    if (idx >= IMG * IMG) return;
    int y0 = idx / IMG, x0 = idx % IMG;
    int y = y0 + PADR, x = x0 + PADR;
    float num = 0.f, den = 0.f;
#pragma unroll
    for (int i = 0; i < PS; i++)
#pragma unroll
        for (int j = 0; j < PS; j++) {
            int a = y - i, b = x - j;
            num += Xsum[(i * PS + j) * LTOT + a * XDIM + b];
            den += Wacc[a * XDIM + b];
        }
    out[idx] = num / den;
}

static size_t sh_bytes(int m)
{
    int NCp = m + PP + 1;
    return (size_t)(m * 50 * 2 + m * m + m * NCp + m) * sizeof(float);
}

extern "C" void kernel_launch(void* const* d_in, const int* in_sizes, int n_in,
                              void* d_out, int out_size, void* d_ws, size_t ws_size,
                              hipStream_t stream)
{
    const float* input = (const float*)d_in[0];
    const float* sigma = (const float*)d_in[1];
    float* out = (float*)d_out;

    char* ws = (char*)d_ws;
    float* padY = (float*)ws; ws += (size_t)PDIM * PDIM * 4;
    float* padX = (float*)ws; ws += (size_t)PDIM * PDIM * 4;
    float* den1 = (float*)ws; ws += (size_t)IMG * IMG * 4;
    int*   pos  = (int*)ws;   ws += (size_t)NBLK * MM2 * 4;
    float* Xsum = (float*)ws; ws += (size_t)PP * LTOT * 4;
    float* Wacc = (float*)ws; ws += (size_t)LTOT * 4;

    const int padBlocks = (PDIM * PDIM + 255) / 256;
    const int imgBlocks = (IMG * IMG + 255) / 256;

    // ---- stage 1 ----
    hipMemsetAsync(Xsum, 0, (size_t)PP * LTOT * 4, stream);
    hipMemsetAsync(Wacc, 0, (size_t)LTOT * 4, stream);
    pad_reflect<<<padBlocks, 256, 0, stream>>>(input, padY);
    block_match<<<dim3(GDIM, GDIM), 256, 0, stream>>>(padY, pos, MM1);
    denoise_scatter<<<NBLK, 256, sh_bytes(MM1), stream>>>(padY, padY, pos, sigma,
                                                          Xsum, Wacc, MM1, 0);
    fold_norm<<<imgBlocks, 256, 0, stream>>>(Xsum, Wacc, den1);

    // ---- stage 2 ----
    pad_reflect<<<padBlocks, 256, 0, stream>>>(den1, padX);
    hipMemsetAsync(Xsum, 0, (size_t)PP * LTOT * 4, stream);
    hipMemsetAsync(Wacc, 0, (size_t)LTOT * 4, stream);
    block_match<<<dim3(GDIM, GDIM), 256, 0, stream>>>(padX, pos, MM2);
    denoise_scatter<<<NBLK, 256, sh_bytes(MM2), stream>>>(padY, padX, pos, sigma,
                                                          Xsum, Wacc, MM2, 1);
    fold_norm<<<imgBlocks, 256, 0, stream>>>(Xsum, Wacc, out);
}

// Round 2
// 1618.898 us; speedup vs baseline: 1.3778x; 1.3778x over previous
//
#include <hip/hip_runtime.h>
#include <math.h>
#include <float.h>

// ---- problem constants (N=1, C=1, 256x256, sigma scalar) ----
constexpr int IMG  = 256;            // H = W
constexpr int PADR = 21;             // p//2 + w//2 = 3 + 18
constexpr int PDIM = IMG + 2*PADR;   // 298
constexpr int XDIM = PDIM - 7 + 1;   // 292  (unfold spatial dim)
constexpr int LTOT = XDIM * XDIM;    // 85264
constexpr int WSZ  = 37;             // search window
constexpr int INC  = 18;             // WSZ/2
constexpr int ST   = 4;              // stride
constexpr int GDIM = 64;             // query grid per dim (256/4)
constexpr int NBLK = GDIM * GDIM;    // 4096
constexpr int PS   = 7;              // patch size
constexpr int PP   = 49;             // patch pixels
constexpr int MM1  = 18;
constexpr int MM2  = 55;
constexpr int RG   = 43;             // search region = 2*INC + PS

// ---------------- reflect pad: src (IMG x IMG) -> dst (PDIM x PDIM) ----------
__global__ void pad_reflect(const float* __restrict__ src, float* __restrict__ dst)
{
    int idx = blockIdx.x * 256 + threadIdx.x;
    if (idx >= PDIM * PDIM) return;
    int y = idx / PDIM, x = idx % PDIM;
    int oy = y - PADR; oy = (oy < 0) ? -oy : ((oy >= IMG) ? 2*(IMG-1) - oy : oy);
    int ox = x - PADR; ox = (ox < 0) ? -ox : ((ox >= IMG) ? 2*(IMG-1) - ox : ox);
    dst[idx] = src[oy * IMG + ox];
}

// ---------------- block matching: one workgroup per query block -------------
__global__ __launch_bounds__(256) void block_match(const float* __restrict__ pad,
                                                   int* __restrict__ pos, int m)
{
    __shared__ float reg[RG][RG + 1];
    __shared__ float dist[WSZ * WSZ];
    __shared__ float sv[4];
    __shared__ int   si[4];

    const int gi = blockIdx.y, gj = blockIdx.x;
    const int tid = threadIdx.x;
    const int r0 = ST * gi, c0 = ST * gj;       // region top-left in padded coords

    for (int t = tid; t < RG * RG; t += 256) {
        int r = t / RG, c = t % RG;
        reg[r][c] = pad[(r0 + r) * PDIM + (c0 + c)];
    }
    __syncthreads();

    float q[PP];
#pragma unroll
    for (int i = 0; i < PS; i++)
#pragma unroll
        for (int j = 0; j < PS; j++)
            q[i * PS + j] = reg[INC + i][INC + j];

    for (int o = tid; o < WSZ * WSZ; o += 256) {
        int oi = o / WSZ, oj = o % WSZ;
        float s = 0.f;
#pragma unroll
        for (int i = 0; i < PS; i++)
#pragma unroll
            for (int j = 0; j < PS; j++) {
                float d = reg[oi + i][oj + j] - q[i * PS + j];
                s += d * d;
            }
        dist[o] = s;
    }
    __syncthreads();
    if (tid == 0) dist[INC * WSZ + INC] = -1.0f;   // self match
    __syncthreads();

    const int blk = gi * GDIM + gj;
    for (int sel = 0; sel < m; sel++) {
        float bv = FLT_MAX; int bi = WSZ * WSZ;
        for (int o = tid; o < WSZ * WSZ; o += 256) {
            float v = dist[o];
            if (v < bv || (v == bv && o < bi)) { bv = v; bi = o; }
        }
        for (int d = 32; d > 0; d >>= 1) {
            float ov = __shfl_down(bv, d);
            int   oo = __shfl_down(bi, d);
            if (ov < bv || (ov == bv && oo < bi)) { bv = ov; bi = oo; }
        }
        if ((tid & 63) == 0) { sv[tid >> 6] = bv; si[tid >> 6] = bi; }
        __syncthreads();
        if (tid == 0) {
            float fv = sv[0]; int fi = si[0];
            for (int wv = 1; wv < 4; wv++)
                if (sv[wv] < fv || (sv[wv] == fv && si[wv] < fi)) { fv = sv[wv]; fi = si[wv]; }
            int oi = fi / WSZ, oj = fi % WSZ;
            pos[blk * m + sel] = (oi + ST * gi) * XDIM + (oj + ST * gj);
            dist[fi] = FLT_MAX;
        }
        __syncthreads();
    }
}

// ---------------- denoise + scatter: one workgroup per group ----------------
// M = Gram(S) (+ c*I if ADDC); Minv via parallel Gauss-Jordan (SPD, no pivot).
// theta = I - c*Minv; Xh = Y - c*(Minv Y); w_k = 1/sum_j theta_kj^2.
// Scatter patch pixel (i,j) of pos (a,b): Num[a+i][b+j] += w_k*xh; Wacc[pos]+=w_k.
template<int M_, bool ADDC>
__global__ __launch_bounds__(256) void denoise_scatter(
    const float* __restrict__ padY, const float* __restrict__ padS,
    const int* __restrict__ pos, const float* __restrict__ sigma_p,
    float* __restrict__ Num, float* __restrict__ Wacc)
{
    constexpr int MP  = (M_ % 2 == 0) ? M_ + 1 : M_ + 2;   // odd row stride
    constexpr int IVW = (MP > 50) ? MP : 50;               // Iv doubles as Ssh

    __shared__ float Ysh[M_ * 50];
    __shared__ float Msh[M_ * MP];
    __shared__ float Iv [M_ * IVW];
    __shared__ float prow[MP], prowI[MP], colk[M_];
    __shared__ float wsh[M_];
    __shared__ float pivinv_s;

    const int tid = threadIdx.x;
    const int blk = blockIdx.x;
    const float sg = *sigma_p;
    const float c  = (float)PP * sg * sg;

    // gather group patches (S staged into Iv buffer, stride 50)
    for (int t = tid; t < M_ * PP; t += 256) {
        int k = t / PP, qq = t % PP;
        int p_ = pos[blk * M_ + k];
        int a = p_ / XDIM, b = p_ % XDIM;
        int g = (a + qq / PS) * PDIM + (b + qq % PS);
        Ysh[k * 50 + qq] = padY[g];
        Iv [k * 50 + qq] = padS[g];
    }
    __syncthreads();

    // full Gram into Msh
    for (int t = tid; t < M_ * M_; t += 256) {
        int i = t / M_, j = t - (t / M_) * M_;
        float acc = 0.f;
#pragma unroll
        for (int q = 0; q < PP; q++) acc += Iv[i * 50 + q] * Iv[j * 50 + q];
        if (ADDC && i == j) acc += c;
        Msh[i * MP + j] = acc;
    }
    __syncthreads();

    // Iv = I
    for (int t = tid; t < M_ * M_; t += 256) {
        int i = t / M_, j = t - (t / M_) * M_;
        Iv[i * MP + j] = (i == j) ? 1.f : 0.f;
    }
    __syncthreads();

    // Gauss-Jordan: M -> I, Iv -> M^{-1}
    for (int k = 0; k < M_; k++) {
        // phase A: snapshot pivot row / column (disjoint thread ranges)
        if (tid < M_)                        colk[tid] = Msh[tid * MP + k];
        else if (tid >= 64  && tid < 64  + M_) prow [tid - 64 ] = Msh[k * MP + (tid - 64)];
        else if (tid >= 128 && tid < 128 + M_) prowI[tid - 128] = Iv [k * MP + (tid - 128)];
        else if (tid == 224)                 pivinv_s = 1.f / Msh[k * MP + k];
        __syncthreads();
        const float pv = pivinv_s;
        for (int t = tid; t < 2 * M_ * M_; t += 256) {
            int u = (t >= M_ * M_) ? t - M_ * M_ : t;
            int r = u / M_, j = u - r * M_;
            float p = ((t >= M_ * M_) ? prowI[j] : prow[j]) * pv;
            float* A = (t >= M_ * M_) ? Iv : Msh;
            if (r == k) A[r * MP + j] = p;
            else        A[r * MP + j] -= colk[r] * p;
        }
        __syncthreads();
    }

    // weights: 1 / rowsum(theta^2), theta = I - c*Minv
    if (tid < M_) {
        float s = 0.f;
#pragma unroll
        for (int j = 0; j < M_; j++) {
            float th = ((j == tid) ? 1.f : 0.f) - c * Iv[tid * MP + j];
            s += th * th;
        }
        wsh[tid] = 1.f / s;
    }
    __syncthreads();

    // scatter: fused Xh = Y - c*(Minv Y), direct into output-resolution Num
    for (int t = tid; t < M_ * PP; t += 256) {
        int k = t / PP, qq = t - (t / PP) * PP;
        float z = 0.f;
#pragma unroll
        for (int j = 0; j < M_; j++) z += Iv[k * MP + j] * Ysh[j * 50 + qq];
        float xh = Ysh[k * 50 + qq] - c * z;
        int p_ = pos[blk * M_ + k];
        int a = p_ / XDIM, b = p_ - (p_ / XDIM) * XDIM;
        atomicAdd(&Num[(a + qq / PS) * PDIM + (b + qq % PS)], xh * wsh[k]);
    }
    for (int t = tid; t < M_; t += 256)
        atomicAdd(&Wacc[pos[blk * M_ + t]], wsh[t]);
}

// ---------------- normalize + crop (den = 49-tap fold of Wacc) --------------
__global__ void fold_norm(const float* __restrict__ Num, const float* __restrict__ Wacc,
                          float* __restrict__ out)
{
    int idx = blockIdx.x * 256 + threadIdx.x;
    if (idx >= IMG * IMG) return;
    int y0 = idx / IMG, x0 = idx % IMG;
    int y = y0 + PADR, x = x0 + PADR;
    float den = 0.f;
#pragma unroll
    for (int i = 0; i < PS; i++)
#pragma unroll
        for (int j = 0; j < PS; j++)
            den += Wacc[(y - i) * XDIM + (x - j)];
    out[idx] = Num[y * PDIM + x] / den;
}

extern "C" void kernel_launch(void* const* d_in, const int* in_sizes, int n_in,
                              void* d_out, int out_size, void* d_ws, size_t ws_size,
                              hipStream_t stream)
{
    const float* input = (const float*)d_in[0];
    const float* sigma = (const float*)d_in[1];
    float* out = (float*)d_out;

    char* ws = (char*)d_ws;
    float* padY = (float*)ws; ws += (size_t)PDIM * PDIM * 4;
    float* padX = (float*)ws; ws += (size_t)PDIM * PDIM * 4;
    float* den1 = (float*)ws; ws += (size_t)IMG * IMG * 4;
    int*   pos  = (int*)ws;   ws += (size_t)NBLK * MM2 * 4;
    float* Num  = (float*)ws; ws += (size_t)PDIM * PDIM * 4;
    float* Wacc = (float*)ws; ws += (size_t)LTOT * 4;

    const int padBlocks = (PDIM * PDIM + 255) / 256;
    const int imgBlocks = (IMG * IMG + 255) / 256;

    // ---- stage 1 ----
    hipMemsetAsync(Num,  0, (size_t)PDIM * PDIM * 4, stream);
    hipMemsetAsync(Wacc, 0, (size_t)LTOT * 4, stream);
    pad_reflect<<<padBlocks, 256, 0, stream>>>(input, padY);
    block_match<<<dim3(GDIM, GDIM), 256, 0, stream>>>(padY, pos, MM1);
    denoise_scatter<MM1, false><<<NBLK, 256, 0, stream>>>(padY, padY, pos, sigma, Num, Wacc);
    fold_norm<<<imgBlocks, 256, 0, stream>>>(Num, Wacc, den1);

    // ---- stage 2 ----
    pad_reflect<<<padBlocks, 256, 0, stream>>>(den1, padX);
    hipMemsetAsync(Num,  0, (size_t)PDIM * PDIM * 4, stream);
    hipMemsetAsync(Wacc, 0, (size_t)LTOT * 4, stream);
    block_match<<<dim3(GDIM, GDIM), 256, 0, stream>>>(padX, pos, MM2);
    denoise_scatter<MM2, true><<<NBLK, 256, 0, stream>>>(padY, padX, pos, sigma, Num, Wacc);
    fold_norm<<<imgBlocks, 256, 0, stream>>>(Num, Wacc, out);
}

// Round 3
// 1085.706 us; speedup vs baseline: 2.0544x; 1.4911x over previous
//
#include <hip/hip_runtime.h>
#include <math.h>
#include <float.h>

// ---- problem constants (N=1, C=1, 256x256, sigma scalar) ----
constexpr int IMG  = 256;            // H = W
constexpr int PADR = 21;             // p//2 + w//2 = 3 + 18
constexpr int PDIM = IMG + 2*PADR;   // 298
constexpr int XDIM = PDIM - 7 + 1;   // 292  (unfold spatial dim)
constexpr int LTOT = XDIM * XDIM;    // 85264
constexpr int WSZ  = 37;             // search window
constexpr int INC  = 18;             // WSZ/2
constexpr int ST   = 4;              // stride
constexpr int GDIM = 64;             // query grid per dim (256/4)
constexpr int NBLK = GDIM * GDIM;    // 4096
constexpr int PS   = 7;              // patch size
constexpr int PP   = 49;             // patch pixels
constexpr int MM1  = 18;
constexpr int MM2  = 55;
constexpr int RG   = 43;             // search region = 2*INC + PS
constexpr int NOFF = WSZ * WSZ;      // 1369
constexpr int UCAP = (NOFF + 63) / 64;  // 22 dist values cached per lane

// ---------------- reflect pad: src (IMG x IMG) -> dst (PDIM x PDIM) ----------
__global__ void pad_reflect(const float* __restrict__ src, float* __restrict__ dst)
{
    int idx = blockIdx.x * 256 + threadIdx.x;
    if (idx >= PDIM * PDIM) return;
    int y = idx / PDIM, x = idx % PDIM;
    int oy = y - PADR; oy = (oy < 0) ? -oy : ((oy >= IMG) ? 2*(IMG-1) - oy : oy);
    int ox = x - PADR; ox = (ox < 0) ? -ox : ((ox >= IMG) ? 2*(IMG-1) - ox : ox);
    dst[idx] = src[oy * IMG + ox];
}

// ---------------- block matching: one workgroup per query block -------------
// Top-m selection entirely on wave 0 in registers (no barriers in the loop).
__global__ __launch_bounds__(256) void block_match(const float* __restrict__ pad,
                                                   int* __restrict__ pos, int m)
{
    __shared__ float reg[RG][RG + 1];
    __shared__ float dist[NOFF];

    const int gi = blockIdx.y, gj = blockIdx.x;
    const int tid = threadIdx.x;
    const int r0 = ST * gi, c0 = ST * gj;

    for (int t = tid; t < RG * RG; t += 256) {
        int r = t / RG, c = t % RG;
        reg[r][c] = pad[(r0 + r) * PDIM + (c0 + c)];
    }
    __syncthreads();

    float q[PP];
#pragma unroll
    for (int i = 0; i < PS; i++)
#pragma unroll
        for (int j = 0; j < PS; j++)
            q[i * PS + j] = reg[INC + i][INC + j];

    for (int o = tid; o < NOFF; o += 256) {
        int oi = o / WSZ, oj = o % WSZ;
        float s = 0.f;
#pragma unroll
        for (int i = 0; i < PS; i++)
#pragma unroll
            for (int j = 0; j < PS; j++) {
                float d = reg[oi + i][oj + j] - q[i * PS + j];
                s += d * d;
            }
        dist[o] = (o == INC * WSZ + INC) ? -1.0f : s;   // self match sentinel
    }
    __syncthreads();

    if (tid >= 64) return;        // selection runs on wave 0 only
    const int lane = tid;

    // cache dist into registers: lane owns o = lane + 64*u
    float dv[UCAP];
#pragma unroll
    for (int u = 0; u < UCAP; u++) {
        int o = lane + (u << 6);
        dv[u] = (o < NOFF) ? dist[o] : FLT_MAX;
    }

    const int blk = gi * GDIM + gj;
    for (int sel = 0; sel < m; sel++) {
        float bv = dv[0]; int bo = lane;
#pragma unroll
        for (int u = 1; u < UCAP; u++) {
            int o = lane + (u << 6);
            if (dv[u] < bv) { bv = dv[u]; bo = o; }
        }
        // 64-lane butterfly argmin (tie -> lower index, matching top_k order)
#pragma unroll
        for (int d = 1; d < 64; d <<= 1) {
            float ov = __shfl_xor(bv, d);
            int   oo = __shfl_xor(bo, d);
            if (ov < bv || (ov == bv && oo < bo)) { bv = ov; bo = oo; }
        }
        if (lane == 0) {
            int oi = bo / WSZ, oj = bo % WSZ;
            pos[blk * m + sel] = (oi + ST * gi) * XDIM + (oj + ST * gj);
        }
        // winner's owner removes it locally
#pragma unroll
        for (int u = 0; u < UCAP; u++)
            if (bo == lane + (u << 6)) dv[u] = FLT_MAX;
    }
}

// ---------------- denoise + scatter: one workgroup per group ----------------
// M = Gram(S) (+ c*I if ADDC). Inversion: symmetric sweep operator on wave 0,
// column-per-lane in registers (A -> -A^{-1}), broadcast via v_readlane.
// theta = I - c*Minv; Xh = Y - c*(Minv Y); w_k = 1/rowsum(theta^2).
template<int M_, bool ADDC>
__global__ __launch_bounds__(256) void denoise_scatter(
    const float* __restrict__ padY, const float* __restrict__ padS,
    const int* __restrict__ pos, const float* __restrict__ sigma_p,
    float* __restrict__ Num, float* __restrict__ Wacc)
{
    constexpr int MP = (M_ + 4) & ~3;        // Msh row stride (mult of 4): 56 / 20
    constexpr int SS = 52;                   // Ssh row stride (13*16B, zero-padded)
    constexpr int YS = 60;                   // Yt  row stride (15*16B)

    __shared__ __align__(16) float Ssh[M_ * SS];
    __shared__ __align__(16) float Yt [PP * YS];   // Yt[qq][k] = Y patch k, pixel qq
    __shared__ __align__(16) float Msh[M_ * MP];
    __shared__ float wsh[M_];
    __shared__ int   posh[M_];

    const int tid = threadIdx.x;
    const int blk = blockIdx.x;
    const float sg = *sigma_p;
    const float c  = (float)PP * sg * sg;

    if (tid < M_) posh[tid] = pos[blk * M_ + tid];
    __syncthreads();

    // gather A: Ssh row-major (stride-1 LDS writes), cols 49..51 zeroed
    for (int t = tid; t < M_ * SS; t += 256) {
        int k = t / SS, qq = t - k * SS;
        float v = 0.f;
        if (qq < PP) {
            int p_ = posh[k];
            int a = p_ / XDIM, b = p_ - (p_ / XDIM) * XDIM;
            v = padS[(a + qq / PS) * PDIM + (b + qq % PS)];
        }
        Ssh[t] = v;
    }
    // gather B: Yt transposed (k fastest -> stride-1 LDS writes)
    for (int t = tid; t < PP * M_; t += 256) {
        int qq = t / M_, k = t - qq * M_;
        int p_ = posh[k];
        int a = p_ / XDIM, b = p_ - (p_ / XDIM) * XDIM;
        Yt[qq * YS + k] = padY[(a + qq / PS) * PDIM + (b + qq % PS)];
    }
    __syncthreads();

    // Gram, lower triangle only, float4 over q
    for (int t = tid; t < M_ * M_; t += 256) {
        int i = t / M_, j = t - i * M_;
        if (j > i) continue;
        const float4* Si = (const float4*)&Ssh[i * SS];
        const float4* Sj = (const float4*)&Ssh[j * SS];
        float acc = 0.f;
#pragma unroll
        for (int cch = 0; cch < SS / 4; cch++) {
            float4 a4 = Si[cch], b4 = Sj[cch];
            acc += a4.x * b4.x + a4.y * b4.y + a4.z * b4.z + a4.w * b4.w;
        }
        if (ADDC && i == j) acc += c;
        Msh[i * MP + j] = acc;
    }
    __syncthreads();

    // ---- symmetric sweep inversion on wave 0 (register columns) ----
    if (tid < 64) {
        const int j = (tid < M_) ? tid : (M_ - 1);   // clamp extra lanes
        float col[M_];
#pragma unroll
        for (int i = 0; i < M_; i++)
            col[i] = Msh[(i >= j) ? (i * MP + j) : (j * MP + i)];

#pragma unroll
        for (int k = 0; k < M_; k++) {
            float d = __int_as_float(__builtin_amdgcn_readlane(__float_as_int(col[k]), k));
            d = (fabsf(d) > 1e-30f) ? d : 1e-30f;
            float dinv = 1.0f / d;
            float cks = col[k];
            float f  = (j == k) ? (1.0f - dinv) : (cks * dinv);
            float fn = -f;
#pragma unroll
            for (int i = 0; i < M_; i++) {
                if (i == k) continue;
                float aik = __int_as_float(__builtin_amdgcn_readlane(__float_as_int(cks), i));
                col[i] = fmaf(aik, fn, col[i]);
            }
            col[k] = (j == k) ? (-dinv) : (cks * dinv);
        }
        // now col = column j of -M^{-1}
        if (tid < M_) {
            float s = 0.f;
#pragma unroll
            for (int i = 0; i < M_; i++) {
                float th = fmaf(c, col[i], (i == j) ? 1.f : 0.f);  // I - c*Minv
                s = fmaf(th, th, s);
            }
            wsh[j] = 1.0f / s;
#pragma unroll
            for (int i = 0; i < M_; i++)
                Msh[i * MP + j] = -col[i];                          // Minv (full)
        }
    }
    __syncthreads();

    // ---- Z = Minv*Y fused with weighted scatter into Num ----
    for (int t = tid; t < M_ * PP; t += 256) {
        int k = t / PP, qq = t - k * PP;
        const float4* Mi = (const float4*)&Msh[k * MP];
        const float4* Yq = (const float4*)&Yt [qq * YS];
        float z = 0.f;
#pragma unroll
        for (int cch = 0; cch < M_ / 4; cch++) {
            float4 a4 = Mi[cch], b4 = Yq[cch];
            z += a4.x * b4.x + a4.y * b4.y + a4.z * b4.z + a4.w * b4.w;
        }
#pragma unroll
        for (int jj = (M_ / 4) * 4; jj < M_; jj++)
            z += Msh[k * MP + jj] * Yt[qq * YS + jj];
        float xh = Yt[qq * YS + k] - c * z;
        int p_ = posh[k];
        int a = p_ / XDIM, b = p_ - (p_ / XDIM) * XDIM;
        atomicAdd(&Num[(a + qq / PS) * PDIM + (b + qq % PS)], xh * wsh[k]);
    }
    for (int t = tid; t < M_; t += 256)
        atomicAdd(&Wacc[posh[t]], wsh[t]);
}

// ---------------- normalize + crop (den = 49-tap fold of Wacc) --------------
__global__ void fold_norm(const float* __restrict__ Num, const float* __restrict__ Wacc,
                          float* __restrict__ out)
{
    int idx = blockIdx.x * 256 + threadIdx.x;
    if (idx >= IMG * IMG) return;
    int y0 = idx / IMG, x0 = idx % IMG;
    int y = y0 + PADR, x = x0 + PADR;
    float den = 0.f;
#pragma unroll
    for (int i = 0; i < PS; i++)
#pragma unroll
        for (int j = 0; j < PS; j++)
            den += Wacc[(y - i) * XDIM + (x - j)];
    out[idx] = Num[y * PDIM + x] / den;
}

extern "C" void kernel_launch(void* const* d_in, const int* in_sizes, int n_in,
                              void* d_out, int out_size, void* d_ws, size_t ws_size,
                              hipStream_t stream)
{
    const float* input = (const float*)d_in[0];
    const float* sigma = (const float*)d_in[1];
    float* out = (float*)d_out;

    char* ws = (char*)d_ws;
    float* padY = (float*)ws; ws += (size_t)PDIM * PDIM * 4;
    float* padX = (float*)ws; ws += (size_t)PDIM * PDIM * 4;
    float* den1 = (float*)ws; ws += (size_t)IMG * IMG * 4;
    int*   pos  = (int*)ws;   ws += (size_t)NBLK * MM2 * 4;
    float* Num  = (float*)ws; ws += (size_t)PDIM * PDIM * 4;
    float* Wacc = (float*)ws; ws += (size_t)LTOT * 4;

    const int padBlocks = (PDIM * PDIM + 255) / 256;
    const int imgBlocks = (IMG * IMG + 255) / 256;

    // ---- stage 1 ----
    hipMemsetAsync(Num,  0, (size_t)PDIM * PDIM * 4, stream);
    hipMemsetAsync(Wacc, 0, (size_t)LTOT * 4, stream);
    pad_reflect<<<padBlocks, 256, 0, stream>>>(input, padY);
    block_match<<<dim3(GDIM, GDIM), 256, 0, stream>>>(padY, pos, MM1);
    denoise_scatter<MM1, false><<<NBLK, 256, 0, stream>>>(padY, padY, pos, sigma, Num, Wacc);
    fold_norm<<<imgBlocks, 256, 0, stream>>>(Num, Wacc, den1);

    // ---- stage 2 ----
    pad_reflect<<<padBlocks, 256, 0, stream>>>(den1, padX);
    hipMemsetAsync(Num,  0, (size_t)PDIM * PDIM * 4, stream);
    hipMemsetAsync(Wacc, 0, (size_t)LTOT * 4, stream);
    block_match<<<dim3(GDIM, GDIM), 256, 0, stream>>>(padX, pos, MM2);
    denoise_scatter<MM2, true><<<NBLK, 256, 0, stream>>>(padY, padX, pos, sigma, Num, Wacc);
    fold_norm<<<imgBlocks, 256, 0, stream>>>(Num, Wacc, out);
}